// Round 12
// baseline (257.539 us; speedup 1.0000x reference)
//
#include <hip/hip_runtime.h>

typedef float  f32x4 __attribute__((ext_vector_type(4)));
typedef float  f32x2 __attribute__((ext_vector_type(2)));
typedef short  s16x8 __attribute__((ext_vector_type(8)));

#define BSHIFT 7
#define BMASK  127
#define CHUNK  8192

__device__ __forceinline__ unsigned short f2bf(float f) {
  unsigned int u = __float_as_uint(f);
  unsigned int r = (u + 0x7FFFu + ((u >> 16) & 1u)) >> 16;
  return (unsigned short)r;
}

// ---------------- combined prep: x->bf16 cvt | weight cvt | dst histogram ----------------

__global__ void __launch_bounds__(256) k_prep(
    const float* __restrict__ x, unsigned short* __restrict__ xh, size_t total8, int cvtBlocks,
    const float* __restrict__ W0, const float* __restrict__ W1,
    const float* __restrict__ W2, const float* __restrict__ W3,
    unsigned short* __restrict__ B0, unsigned short* __restrict__ B1,
    unsigned short* __restrict__ B2, unsigned short* __restrict__ B3,
    const int* __restrict__ ei, int E, int* __restrict__ bhist, int NB) {
  __shared__ int h[1024];
  int b = blockIdx.x;
  if (b < cvtBlocks) {
    size_t i = (size_t)b * 256 + threadIdx.x;
    if (i >= total8) return;
    float4 a = ((const float4*)x)[i * 2];
    float4 c = ((const float4*)x)[i * 2 + 1];
    uint4 o;
    o.x = (unsigned)f2bf(a.x) | ((unsigned)f2bf(a.y) << 16);
    o.y = (unsigned)f2bf(a.z) | ((unsigned)f2bf(a.w) << 16);
    o.z = (unsigned)f2bf(c.x) | ((unsigned)f2bf(c.y) << 16);
    o.w = (unsigned)f2bf(c.z) | ((unsigned)f2bf(c.w) << 16);
    ((uint4*)xh)[i] = o;
  } else if (b < cvtBlocks + 32) {
    int gt = (b - cvtBlocks) * 256 + threadIdx.x;  // 8192 total
    int which = gt >> 11;
    const float* W = which == 0 ? W0 : which == 1 ? W1 : which == 2 ? W2 : W3;
    unsigned short* WB = which == 0 ? B0 : which == 1 ? B1 : which == 2 ? B2 : B3;
    int t = gt & 2047;
    int lane = t & 63, kt = (t >> 6) & 3, nt = t >> 8;
    int col = nt * 16 + (lane & 15);
    int k0  = kt * 32 + ((lane >> 4) << 3);
#pragma unroll
    for (int j = 0; j < 8; ++j)
      WB[(((nt * 4 + kt) * 64 + lane) << 3) + j] = f2bf(W[(size_t)(k0 + j) * 128 + col]);
  } else {
    int bb = b - cvtBlocks - 32;   // 0..127
    for (int i = threadIdx.x; i < 1024; i += 256) h[i] = 0;
    __syncthreads();
    int i0 = bb * 256 + threadIdx.x;
    int stride = 128 * 256;
    for (int e = i0; e < E; e += stride)
      atomicAdd(&h[ei[E + e] >> BSHIFT], 1);
    __syncthreads();
    for (int i = threadIdx.x; i < NB; i += 256)
      if (h[i]) atomicAdd(&bhist[i], h[i]);
  }
}

// ---------------- bucketed CSR build ----------------

__global__ void k_bscan(const int* __restrict__ bhist, int* __restrict__ boff,
                        int* __restrict__ bcur, int NB, int E) {
  __shared__ int tot[256];
  int t = threadIdx.x;
  int v[4]; int s = 0;
#pragma unroll
  for (int j = 0; j < 4; ++j) {
    int idx = t * 4 + j;
    v[j] = (idx < NB) ? bhist[idx] : 0;
    s += v[j];
  }
  tot[t] = s; __syncthreads();
  for (int off = 1; off < 256; off <<= 1) {
    int x = (t >= off) ? tot[t - off] : 0;
    __syncthreads();
    tot[t] += x;
    __syncthreads();
  }
  int excl = (t > 0) ? tot[t - 1] : 0;
#pragma unroll
  for (int j = 0; j < 4; ++j) {
    int idx = t * 4 + j;
    if (idx < NB) { boff[idx] = excl; bcur[idx] = excl; }
    excl += v[j];
  }
  if (t == 0) boff[NB] = E;
}

__global__ void __launch_bounds__(512) k_part(
    const int* __restrict__ ei, int E, int* __restrict__ bcur,
    unsigned int* __restrict__ tmp, int NB) {
  __shared__ int lh[1024], lbase[1024], lcur[1024];
  int t = threadIdx.x;
  int c0 = blockIdx.x * CHUNK;
  int cend = min(c0 + CHUNK, E);
  for (int i = t; i < NB; i += 512) lh[i] = 0;
  __syncthreads();
  for (int e = c0 + t; e < cend; e += 512)
    atomicAdd(&lh[ei[E + e] >> BSHIFT], 1);
  __syncthreads();
  for (int i = t; i < NB; i += 512) {
    int c = lh[i];
    lbase[i] = c ? atomicAdd(&bcur[i], c) : 0;
    lcur[i] = 0;
  }
  __syncthreads();
  for (int e = c0 + t; e < cend; e += 512) {
    int src = ei[e], dst = ei[E + e];
    int b = dst >> BSHIFT;
    int pos = lbase[b] + atomicAdd(&lcur[b], 1);
    tmp[pos] = ((unsigned)(dst & BMASK) << 25) | (unsigned)src;
  }
}

__global__ void __launch_bounds__(256) k_csr(
    const unsigned int* __restrict__ tmp, const int* __restrict__ boff,
    int* __restrict__ rowptr, int* __restrict__ ssrc, int N, int NB, int E) {
  __shared__ int cnt[128], sc[128], curs[128];
  int b = blockIdx.x;
  int t = threadIdx.x;
  int beg = boff[b], end = boff[b + 1];
  int nbase = b << BSHIFT;
  int nn = min(128, N - nbase);
  if (t < 128) cnt[t] = 0;
  __syncthreads();
  for (int i = beg + t; i < end; i += 256)
    atomicAdd(&cnt[tmp[i] >> 25], 1);
  __syncthreads();
  if (t < 128) sc[t] = cnt[t];
  __syncthreads();
  for (int off = 1; off < 128; off <<= 1) {
    int x = 0;
    if (t < 128 && t >= off) x = sc[t - off];
    __syncthreads();
    if (t < 128) sc[t] += x;
    __syncthreads();
  }
  if (t < nn) {
    int excl = sc[t] - cnt[t];
    rowptr[nbase + t] = beg + excl;
    curs[t] = excl;
  }
  __syncthreads();
  for (int i = beg + t; i < end; i += 256) {
    unsigned int p = tmp[i];
    int pos = beg + atomicAdd(&curs[p >> 25], 1);
    ssrc[pos] = (int)((p & 0x1FFFFFFu) << 8);   // byte offset: src * 256
  }
  if (b == NB - 1 && t == 0) rowptr[N] = E;
}

// ---------------- fused aggregation + MFMA dual matmul + bias + LN partials ----------------
// 128 threads (2 waves) per 16-row tile: each wave gathers 8 rows, then the two
// waves split the MFMA output columns (wave 0: cols 0-63, wave 1: 64-127).
// Grid = N/16 blocks = 2x wave oversubscription -> machine stays full.

__global__ void __launch_bounds__(128, 8) k_fmm(
    const unsigned short* __restrict__ feat, const int* __restrict__ rowptr,
    const int* __restrict__ ssrc,
    const unsigned short* __restrict__ WlB, const unsigned short* __restrict__ WrB,
    const float* __restrict__ bias, unsigned short* __restrict__ out,
    double* __restrict__ red, int N) {
  __shared__ __align__(16) unsigned short aggLds[16 * 136];  // 272B row stride, 4.3KB
  int t = threadIdx.x;
  int wave = t >> 6, l = t & 63;
  int r0 = blockIdx.x * 16;
  const char* fp = (const char*)feat;

  // ---- Phase A: 8 x 16-lane groups, 2 nodes each ----
  {
    int gg = t >> 4;             // 0..7
    int sub = t & 15;            // 16B slice
    unsigned suboff = (unsigned)(sub * 16);
#pragma unroll
    for (int j = 0; j < 2; ++j) {
      int row = gg * 2 + j;      // 0..15
      int node = r0 + row;
      uint4 o = make_uint4(0, 0, 0, 0);
      if (node < N) {
        int beg = rowptr[node], end = rowptr[node + 1];
        f32x2 a0 = {0.f, 0.f}, a1 = a0, a2 = a0, a3 = a0;
#define ACCQ(q) {                                                    \
          a0 += (f32x2){__uint_as_float((q).x << 16),                \
                        __uint_as_float((q).x & 0xFFFF0000u)};       \
          a1 += (f32x2){__uint_as_float((q).y << 16),                \
                        __uint_as_float((q).y & 0xFFFF0000u)};       \
          a2 += (f32x2){__uint_as_float((q).z << 16),                \
                        __uint_as_float((q).z & 0xFFFF0000u)};       \
          a3 += (f32x2){__uint_as_float((q).w << 16),                \
                        __uint_as_float((q).w & 0xFFFF0000u)};       \
        }
        int i = beg;
        for (; i + 4 <= end; i += 4) {
          unsigned o0 = (unsigned)ssrc[i]     + suboff;
          unsigned o1 = (unsigned)ssrc[i + 1] + suboff;
          unsigned o2 = (unsigned)ssrc[i + 2] + suboff;
          unsigned o3 = (unsigned)ssrc[i + 3] + suboff;
          uint4 q0 = *(const uint4*)(fp + o0);
          uint4 q1 = *(const uint4*)(fp + o1);
          uint4 q2 = *(const uint4*)(fp + o2);
          uint4 q3 = *(const uint4*)(fp + o3);
          ACCQ(q0); ACCQ(q1); ACCQ(q2); ACCQ(q3);
        }
        for (; i < end; ++i) {
          uint4 q = *(const uint4*)(fp + ((unsigned)ssrc[i] + suboff));
          ACCQ(q);
        }
#undef ACCQ
        float inv = __builtin_amdgcn_rcpf(fmaxf((float)(end - beg), 1.0f));
        o.x = (unsigned)f2bf(a0.x * inv) | ((unsigned)f2bf(a0.y * inv) << 16);
        o.y = (unsigned)f2bf(a1.x * inv) | ((unsigned)f2bf(a1.y * inv) << 16);
        o.z = (unsigned)f2bf(a2.x * inv) | ((unsigned)f2bf(a2.y * inv) << 16);
        o.w = (unsigned)f2bf(a3.x * inv) | ((unsigned)f2bf(a3.y * inv) << 16);
      }
      *(uint4*)&aggLds[row * 136 + sub * 8] = o;
    }
  }
  __syncthreads();

  // ---- Phase B: MFMA, waves split the nt (output-column) dimension ----
  int c = l & 15;
  int rb = (l >> 4) << 2;
  int rowA = r0 + c;
  int rowAc = min(rowA, N - 1);
  const size_t goff = (size_t)rowAc * 128 + ((l >> 4) << 3);
  const unsigned short* aLds = &aggLds[c * 136 + ((l >> 4) << 3)];

  f32x4 acc[4];
#pragma unroll
  for (int ntl = 0; ntl < 4; ++ntl) acc[ntl] = (f32x4){0.f, 0.f, 0.f, 0.f};

#pragma unroll
  for (int kt = 0; kt < 4; ++kt) {
    s16x8 a = *(const s16x8*)(aLds + kt * 32);
#pragma unroll
    for (int ntl = 0; ntl < 4; ++ntl) {
      int nt = wave * 4 + ntl;
      s16x8 b;
      { uint4 q = *(const uint4*)(WlB + (((nt * 4 + kt) * 64 + l) << 3));
        b = *(const s16x8*)&q; }
      acc[ntl] = __builtin_amdgcn_mfma_f32_16x16x32_bf16(a, b, acc[ntl], 0, 0, 0);
    }
  }
#pragma unroll
  for (int kt = 0; kt < 4; ++kt) {
    s16x8 a;
    { uint4 q = *(const uint4*)(feat + goff + kt * 32);
      a = *(const s16x8*)&q; }
#pragma unroll
    for (int ntl = 0; ntl < 4; ++ntl) {
      int nt = wave * 4 + ntl;
      s16x8 b;
      { uint4 q = *(const uint4*)(WrB + (((nt * 4 + kt) * 64 + l) << 3));
        b = *(const s16x8*)&q; }
      acc[ntl] = __builtin_amdgcn_mfma_f32_16x16x32_bf16(a, b, acc[ntl], 0, 0, 0);
    }
  }
  __syncthreads();   // both waves done reading LDS A-data before overwrite

  // ---- Phase C: bias + LN partials; stage own column-half in LDS; store ----
  float s = 0.f, s2 = 0.f;
#pragma unroll
  for (int ntl = 0; ntl < 4; ++ntl) {
    int nt = wave * 4 + ntl;
    float bv = bias[nt * 16 + c];
#pragma unroll
    for (int i = 0; i < 4; ++i) {
      float v = acc[ntl][i] + bv;
      if (r0 + rb + i < N) { s += v; s2 += v * v; }
      aggLds[(rb + i) * 136 + nt * 16 + c] = f2bf(v);
    }
  }
  // wave w wrote cols w*64..w*64+63; read back only own half (wave-local)
#pragma unroll
  for (int j = 0; j < 2; ++j) {
    int idx = j * 64 + l;        // 0..127
    int riw = idx >> 3;          // row 0..15
    int ckl = idx & 7;           // local 16B chunk
    int chunk = wave * 8 + ckl;
    int row = r0 + riw;
    if (row < N) {
      uint4 o = *(const uint4*)&aggLds[riw * 136 + chunk * 8];
      *(uint4*)(out + (size_t)row * 128 + chunk * 8) = o;
    }
  }

#pragma unroll
  for (int off = 1; off < 64; off <<= 1) {
    s  += __shfl_xor(s, off);
    s2 += __shfl_xor(s2, off);
  }
  if (l == 0) {
    int bucket = (blockIdx.x * 2 + wave) & 255;
    atomicAdd(&red[2 * bucket],     (double)s);
    atomicAdd(&red[2 * bucket + 1], (double)s2);
  }
}

// ---------------- normalize + affine + ReLU (stats reduced in-block), bf16 -> bf16 ----------------

__global__ void __launch_bounds__(256) k_apply1(
    const unsigned short* __restrict__ h, unsigned short* __restrict__ o,
    const double* __restrict__ red, double count,
    const float* __restrict__ gamma, const float* __restrict__ beta,
    size_t total8) {
  __shared__ double sh[256], sh2[256];
  __shared__ float sc[2];
  int t = threadIdx.x;
  sh[t] = red[2 * t]; sh2[t] = red[2 * t + 1];
  __syncthreads();
  for (int off = 128; off > 0; off >>= 1) {
    if (t < off) { sh[t] += sh[t + off]; sh2[t] += sh2[t + off]; }
    __syncthreads();
  }
  if (t == 0) {
    double mu = sh[0] / count;
    double var = sh2[0] / count - mu * mu;
    sc[0] = (float)mu;
    sc[1] = (float)(1.0 / sqrt(var + 1e-5));
  }
  __syncthreads();
  size_t i = (size_t)blockIdx.x * blockDim.x + t;
  if (i >= total8) return;
  float mu = sc[0], rs = sc[1];
  int c0 = (int)((i * 8) & 127);
  float4 g0 = *(const float4*)(gamma + c0);
  float4 g1 = *(const float4*)(gamma + c0 + 4);
  float4 b0 = *(const float4*)(beta + c0);
  float4 b1 = *(const float4*)(beta + c0 + 4);
  uint4 q = ((const uint4*)h)[i];
  float gg[8] = {g0.x, g0.y, g0.z, g0.w, g1.x, g1.y, g1.z, g1.w};
  float bb[8] = {b0.x, b0.y, b0.z, b0.w, b1.x, b1.y, b1.z, b1.w};
  uint4 ov;
#pragma unroll
  for (int w = 0; w < 4; ++w) {
    unsigned int v = ((const unsigned int*)&q)[w];
    float x0 = __uint_as_float(v << 16);
    float x1 = __uint_as_float(v & 0xFFFF0000u);
    float y0 = fmaxf((x0 - mu) * rs * gg[2 * w] + bb[2 * w], 0.f);
    float y1 = fmaxf((x1 - mu) * rs * gg[2 * w + 1] + bb[2 * w + 1], 0.f);
    ((unsigned int*)&ov)[w] = (unsigned)f2bf(y0) | ((unsigned)f2bf(y1) << 16);
  }
  ((uint4*)o)[i] = ov;
}

// ---------------- normalize + affine + ReLU + residual(bf16) -> fp32 ----------------

__global__ void __launch_bounds__(256) k_apply2(
    const unsigned short* __restrict__ h, const unsigned short* __restrict__ xres,
    float* __restrict__ o, const double* __restrict__ red, double count,
    const float* __restrict__ gamma, const float* __restrict__ beta,
    size_t total8) {
  __shared__ double sh[256], sh2[256];
  __shared__ float sc[2];
  int t = threadIdx.x;
  sh[t] = red[2 * t]; sh2[t] = red[2 * t + 1];
  __syncthreads();
  for (int off = 128; off > 0; off >>= 1) {
    if (t < off) { sh[t] += sh[t + off]; sh2[t] += sh2[t + off]; }
    __syncthreads();
  }
  if (t == 0) {
    double mu = sh[0] / count;
    double var = sh2[0] / count - mu * mu;
    sc[0] = (float)mu;
    sc[1] = (float)(1.0 / sqrt(var + 1e-5));
  }
  __syncthreads();
  size_t i = (size_t)blockIdx.x * blockDim.x + t;
  if (i >= total8) return;
  float mu = sc[0], rs = sc[1];
  int c0 = (int)((i * 8) & 127);
  float4 g0 = *(const float4*)(gamma + c0);
  float4 g1 = *(const float4*)(gamma + c0 + 4);
  float4 b0 = *(const float4*)(beta + c0);
  float4 b1 = *(const float4*)(beta + c0 + 4);
  uint4 q  = ((const uint4*)h)[i];
  uint4 qx = ((const uint4*)xres)[i];
  float gg[8] = {g0.x, g0.y, g0.z, g0.w, g1.x, g1.y, g1.z, g1.w};
  float bb[8] = {b0.x, b0.y, b0.z, b0.w, b1.x, b1.y, b1.z, b1.w};
  float out8[8];
#pragma unroll
  for (int w = 0; w < 4; ++w) {
    unsigned int v  = ((const unsigned int*)&q)[w];
    unsigned int vx = ((const unsigned int*)&qx)[w];
    float x0 = __uint_as_float(v << 16);
    float x1 = __uint_as_float(v & 0xFFFF0000u);
    float r0 = __uint_as_float(vx << 16);
    float r1 = __uint_as_float(vx & 0xFFFF0000u);
    out8[2 * w]     = fmaxf((x0 - mu) * rs * gg[2 * w] + bb[2 * w], 0.f) + r0;
    out8[2 * w + 1] = fmaxf((x1 - mu) * rs * gg[2 * w + 1] + bb[2 * w + 1], 0.f) + r1;
  }
  ((float4*)o)[i * 2]     = make_float4(out8[0], out8[1], out8[2], out8[3]);
  ((float4*)o)[i * 2 + 1] = make_float4(out8[4], out8[5], out8[6], out8[7]);
}

// ---------------- launch ----------------

extern "C" void kernel_launch(void* const* d_in, const int* in_sizes, int n_in,
                              void* d_out, int out_size, void* d_ws, size_t ws_size,
                              hipStream_t stream) {
  const float* x   = (const float*)d_in[0];
  const int*   ei  = (const int*)d_in[1];
  const float* Wl1 = (const float*)d_in[2];
  const float* bl1 = (const float*)d_in[3];
  const float* Wr1 = (const float*)d_in[4];
  const float* g1  = (const float*)d_in[5];
  const float* b1  = (const float*)d_in[6];
  const float* Wl2 = (const float*)d_in[7];
  const float* bl2 = (const float*)d_in[8];
  const float* Wr2 = (const float*)d_in[9];
  const float* g2  = (const float*)d_in[10];
  const float* b2  = (const float*)d_in[11];
  float* out = (float*)d_out;

  const int N = in_sizes[0] / 128;
  const int E = in_sizes[1] / 2;
  const int NB = (N + BMASK) >> BSHIFT;

  char* ws = (char*)d_ws;
  size_t off = 0;
  auto alloc = [&](size_t bytes) -> void* {
    void* p = ws + off;
    off = (off + bytes + 255) & ~(size_t)255;
    return p;
  };
  unsigned short* xh   = (unsigned short*)alloc((size_t)N * 128 * 2);
  unsigned short* hmm  = (unsigned short*)alloc((size_t)N * 128 * 2);
  unsigned short* h1n  = (unsigned short*)alloc((size_t)N * 128 * 2);
  int*    ssrc   = (int*)alloc((size_t)E * 4);
  int*    rowptr = (int*)alloc((size_t)(N + 1) * 4);
  int*    bhist  = (int*)alloc((size_t)(NB + 1) * 4);   // contiguous with red: one memset
  double* red    = (double*)alloc(2 * 512 * sizeof(double));
  int*    boff   = (int*)alloc((size_t)(NB + 1) * 4);
  int*    bcur   = (int*)alloc((size_t)(NB + 1) * 4);
  unsigned short* Wl1b = (unsigned short*)alloc(128 * 128 * 2);
  unsigned short* Wr1b = (unsigned short*)alloc(128 * 128 * 2);
  unsigned short* Wl2b = (unsigned short*)alloc(128 * 128 * 2);
  unsigned short* Wr2b = (unsigned short*)alloc(128 * 128 * 2);
  unsigned int* tmp = (unsigned int*)hmm;  // alias: consumed (k_csr) before k_fmm writes hmm
  (void)ws_size; (void)n_in; (void)out_size;

  const size_t total  = (size_t)N * 128;
  const size_t total8 = total / 8;
  const int applyGrid = (int)((total8 + 255) / 256);

  // single memset covers bhist + red (allocated adjacently)
  hipMemsetAsync(bhist, 0, (size_t)((char*)(red + 2 * 512) - (char*)bhist), stream);

  k_prep<<<applyGrid + 32 + 128, 256, 0, stream>>>(
      x, xh, total8, applyGrid,
      Wl1, Wr1, Wl2, Wr2, Wl1b, Wr1b, Wl2b, Wr2b,
      ei, E, bhist, NB);
  k_bscan<<<1, 256, 0, stream>>>(bhist, boff, bcur, NB, E);
  k_part<<<(E + CHUNK - 1) / CHUNK, 512, 0, stream>>>(ei, E, bcur, tmp, NB);
  k_csr<<<NB, 256, 0, stream>>>(tmp, boff, rowptr, ssrc, N, NB, E);

  const int mmGrid = (N + 15) / 16;

  // ---- layer 1 ----
  k_fmm<<<mmGrid, 128, 0, stream>>>(xh, rowptr, ssrc, Wl1b, Wr1b, bl1, hmm, red, N);
  k_apply1<<<applyGrid, 256, 0, stream>>>(hmm, h1n, red, (double)total, g1, b1, total8);

  // ---- layer 2 ----
  k_fmm<<<mmGrid, 128, 0, stream>>>(h1n, rowptr, ssrc, Wl2b, Wr2b, bl2, hmm, red + 512, N);
  k_apply2<<<applyGrid, 256, 0, stream>>>(hmm, xh, out, red + 512, (double)total, g2, b2, total8);
}

// Round 13
// 221.700 us; speedup vs baseline: 1.1617x; 1.1617x over previous
//
#include <hip/hip_runtime.h>

typedef float  f32x4 __attribute__((ext_vector_type(4)));
typedef float  f32x2 __attribute__((ext_vector_type(2)));
typedef short  s16x8 __attribute__((ext_vector_type(8)));

#define BSHIFT 7
#define BMASK  127
#define CHUNK  8192

__device__ __forceinline__ unsigned short f2bf(float f) {
  unsigned int u = __float_as_uint(f);
  unsigned int r = (u + 0x7FFFu + ((u >> 16) & 1u)) >> 16;
  return (unsigned short)r;
}

// pack 8 f32 -> 8 fp8 e4m3 (2 u32) with HW round-to-nearest
__device__ __forceinline__ uint2 pk8_fp8(const float* y) {
  int p0 = __builtin_amdgcn_cvt_pk_fp8_f32(y[0], y[1], 0, false);
  p0     = __builtin_amdgcn_cvt_pk_fp8_f32(y[2], y[3], p0, true);
  int p1 = __builtin_amdgcn_cvt_pk_fp8_f32(y[4], y[5], 0, false);
  p1     = __builtin_amdgcn_cvt_pk_fp8_f32(y[6], y[7], p1, true);
  return make_uint2((unsigned)p0, (unsigned)p1);
}

// ---------------- combined prep: x->bf16+fp8 cvt | weight cvt | dst histogram ----------------

__global__ void __launch_bounds__(256) k_prep(
    const float* __restrict__ x, unsigned short* __restrict__ xh,
    unsigned int* __restrict__ xf8, size_t total8, int cvtBlocks,
    const float* __restrict__ W0, const float* __restrict__ W1,
    const float* __restrict__ W2, const float* __restrict__ W3,
    unsigned short* __restrict__ B0, unsigned short* __restrict__ B1,
    unsigned short* __restrict__ B2, unsigned short* __restrict__ B3,
    const int* __restrict__ ei, int E, int* __restrict__ bhist, int NB) {
  __shared__ int h[1024];
  int b = blockIdx.x;
  if (b < cvtBlocks) {
    size_t i = (size_t)b * 256 + threadIdx.x;
    if (i >= total8) return;
    float4 a = ((const float4*)x)[i * 2];
    float4 c = ((const float4*)x)[i * 2 + 1];
    uint4 o;
    o.x = (unsigned)f2bf(a.x) | ((unsigned)f2bf(a.y) << 16);
    o.y = (unsigned)f2bf(a.z) | ((unsigned)f2bf(a.w) << 16);
    o.z = (unsigned)f2bf(c.x) | ((unsigned)f2bf(c.y) << 16);
    o.w = (unsigned)f2bf(c.z) | ((unsigned)f2bf(c.w) << 16);
    ((uint4*)xh)[i] = o;
    float y[8] = {a.x, a.y, a.z, a.w, c.x, c.y, c.z, c.w};
    ((uint2*)xf8)[i] = pk8_fp8(y);
  } else if (b < cvtBlocks + 32) {
    int gt = (b - cvtBlocks) * 256 + threadIdx.x;  // 8192 total
    int which = gt >> 11;
    const float* W = which == 0 ? W0 : which == 1 ? W1 : which == 2 ? W2 : W3;
    unsigned short* WB = which == 0 ? B0 : which == 1 ? B1 : which == 2 ? B2 : B3;
    int t = gt & 2047;
    int lane = t & 63, kt = (t >> 6) & 3, nt = t >> 8;
    int col = nt * 16 + (lane & 15);
    int k0  = kt * 32 + ((lane >> 4) << 3);
#pragma unroll
    for (int j = 0; j < 8; ++j)
      WB[(((nt * 4 + kt) * 64 + lane) << 3) + j] = f2bf(W[(size_t)(k0 + j) * 128 + col]);
  } else {
    int bb = b - cvtBlocks - 32;   // 0..127
    for (int i = threadIdx.x; i < 1024; i += 256) h[i] = 0;
    __syncthreads();
    int i0 = bb * 256 + threadIdx.x;
    int stride = 128 * 256;
    for (int e = i0; e < E; e += stride)
      atomicAdd(&h[ei[E + e] >> BSHIFT], 1);
    __syncthreads();
    for (int i = threadIdx.x; i < NB; i += 256)
      if (h[i]) atomicAdd(&bhist[i], h[i]);
  }
}

// ---------------- bucketed CSR build ----------------

__global__ void k_bscan(const int* __restrict__ bhist, int* __restrict__ boff,
                        int* __restrict__ bcur, int NB, int E) {
  __shared__ int tot[256];
  int t = threadIdx.x;
  int v[4]; int s = 0;
#pragma unroll
  for (int j = 0; j < 4; ++j) {
    int idx = t * 4 + j;
    v[j] = (idx < NB) ? bhist[idx] : 0;
    s += v[j];
  }
  tot[t] = s; __syncthreads();
  for (int off = 1; off < 256; off <<= 1) {
    int x = (t >= off) ? tot[t - off] : 0;
    __syncthreads();
    tot[t] += x;
    __syncthreads();
  }
  int excl = (t > 0) ? tot[t - 1] : 0;
#pragma unroll
  for (int j = 0; j < 4; ++j) {
    int idx = t * 4 + j;
    if (idx < NB) { boff[idx] = excl; bcur[idx] = excl; }
    excl += v[j];
  }
  if (t == 0) boff[NB] = E;
}

__global__ void __launch_bounds__(512) k_part(
    const int* __restrict__ ei, int E, int* __restrict__ bcur,
    unsigned int* __restrict__ tmp, int NB) {
  __shared__ int lh[1024], lbase[1024], lcur[1024];
  int t = threadIdx.x;
  int c0 = blockIdx.x * CHUNK;
  int cend = min(c0 + CHUNK, E);
  for (int i = t; i < NB; i += 512) lh[i] = 0;
  __syncthreads();
  for (int e = c0 + t; e < cend; e += 512)
    atomicAdd(&lh[ei[E + e] >> BSHIFT], 1);
  __syncthreads();
  for (int i = t; i < NB; i += 512) {
    int c = lh[i];
    lbase[i] = c ? atomicAdd(&bcur[i], c) : 0;
    lcur[i] = 0;
  }
  __syncthreads();
  for (int e = c0 + t; e < cend; e += 512) {
    int src = ei[e], dst = ei[E + e];
    int b = dst >> BSHIFT;
    int pos = lbase[b] + atomicAdd(&lcur[b], 1);
    tmp[pos] = ((unsigned)(dst & BMASK) << 25) | (unsigned)src;
  }
}

__global__ void __launch_bounds__(256) k_csr(
    const unsigned int* __restrict__ tmp, const int* __restrict__ boff,
    int* __restrict__ rowptr, int* __restrict__ ssrc, int N, int NB, int E) {
  __shared__ int cnt[128], sc[128], curs[128];
  int b = blockIdx.x;
  int t = threadIdx.x;
  int beg = boff[b], end = boff[b + 1];
  int nbase = b << BSHIFT;
  int nn = min(128, N - nbase);
  if (t < 128) cnt[t] = 0;
  __syncthreads();
  for (int i = beg + t; i < end; i += 256)
    atomicAdd(&cnt[tmp[i] >> 25], 1);
  __syncthreads();
  if (t < 128) sc[t] = cnt[t];
  __syncthreads();
  for (int off = 1; off < 128; off <<= 1) {
    int x = 0;
    if (t < 128 && t >= off) x = sc[t - off];
    __syncthreads();
    if (t < 128) sc[t] += x;
    __syncthreads();
  }
  if (t < nn) {
    int excl = sc[t] - cnt[t];
    rowptr[nbase + t] = beg + excl;
    curs[t] = excl;
  }
  __syncthreads();
  for (int i = beg + t; i < end; i += 256) {
    unsigned int p = tmp[i];
    int pos = beg + atomicAdd(&curs[p >> 25], 1);
    ssrc[pos] = (int)((p & 0x1FFFFFFu) << 7);   // byte offset into fp8 rows: src * 128
  }
  if (b == NB - 1 && t == 0) rowptr[N] = E;
}

// ---------------- fused fp8-gather aggregation + MFMA dual matmul + LN partials ----------------
// Wave-autonomous (no barriers): wave w owns LDS rows w*16..w*16+15.
// Phase A: 8-lane groups gather 128B fp8 rows (one wave-load = 8 rows).

__global__ void __launch_bounds__(256, 8) k_fmm(
    const unsigned char* __restrict__ featf8, const unsigned short* __restrict__ featbf,
    const int* __restrict__ rowptr, const int* __restrict__ ssrc,
    const unsigned short* __restrict__ WlB, const unsigned short* __restrict__ WrB,
    const float* __restrict__ bias, unsigned short* __restrict__ out,
    double* __restrict__ red, int N) {
  __shared__ __align__(16) unsigned short aggLds[64 * 136];  // 272B row stride
  int t = threadIdx.x;
  int l = t & 63, w = t >> 6;
  const char* fp = (const char*)featf8;

  // ---- Phase A: 8 groups/wave x 8 lanes; each group aggregates 2 nodes ----
  {
    int gg = l >> 3;             // 0..7
    int sub = l & 7;             // 16B slice of 128B fp8 row
    unsigned suboff = (unsigned)(sub * 16);
#pragma unroll
    for (int j = 0; j < 2; ++j) {
      int row = w * 16 + gg * 2 + j;   // wave-local rows
      int node = blockIdx.x * 64 + row;
      if (node < N) {
        int beg = rowptr[node], end = rowptr[node + 1];
        f32x2 a0 = {0.f, 0.f}, a1 = a0, a2 = a0, a3 = a0,
              a4 = a0, a5 = a0, a6 = a0, a7 = a0;
#define ACCQ(q) {                                                        \
          a0 += __builtin_amdgcn_cvt_pk_f32_fp8((q).x, false);           \
          a1 += __builtin_amdgcn_cvt_pk_f32_fp8((q).x, true);            \
          a2 += __builtin_amdgcn_cvt_pk_f32_fp8((q).y, false);           \
          a3 += __builtin_amdgcn_cvt_pk_f32_fp8((q).y, true);            \
          a4 += __builtin_amdgcn_cvt_pk_f32_fp8((q).z, false);           \
          a5 += __builtin_amdgcn_cvt_pk_f32_fp8((q).z, true);            \
          a6 += __builtin_amdgcn_cvt_pk_f32_fp8((q).w, false);           \
          a7 += __builtin_amdgcn_cvt_pk_f32_fp8((q).w, true);            \
        }
        int i = beg;
        for (; i + 4 <= end; i += 4) {
          unsigned o0 = (unsigned)ssrc[i]     + suboff;
          unsigned o1 = (unsigned)ssrc[i + 1] + suboff;
          unsigned o2 = (unsigned)ssrc[i + 2] + suboff;
          unsigned o3 = (unsigned)ssrc[i + 3] + suboff;
          uint4 q0 = *(const uint4*)(fp + o0);
          uint4 q1 = *(const uint4*)(fp + o1);
          uint4 q2 = *(const uint4*)(fp + o2);
          uint4 q3 = *(const uint4*)(fp + o3);
          ACCQ(q0); ACCQ(q1); ACCQ(q2); ACCQ(q3);
        }
        for (; i < end; ++i) {
          uint4 q = *(const uint4*)(fp + ((unsigned)ssrc[i] + suboff));
          ACCQ(q);
        }
#undef ACCQ
        float inv = __builtin_amdgcn_rcpf(fmaxf((float)(end - beg), 1.0f));
        uint4 oa, ob;
        oa.x = (unsigned)f2bf(a0.x * inv) | ((unsigned)f2bf(a0.y * inv) << 16);
        oa.y = (unsigned)f2bf(a1.x * inv) | ((unsigned)f2bf(a1.y * inv) << 16);
        oa.z = (unsigned)f2bf(a2.x * inv) | ((unsigned)f2bf(a2.y * inv) << 16);
        oa.w = (unsigned)f2bf(a3.x * inv) | ((unsigned)f2bf(a3.y * inv) << 16);
        ob.x = (unsigned)f2bf(a4.x * inv) | ((unsigned)f2bf(a4.y * inv) << 16);
        ob.y = (unsigned)f2bf(a5.x * inv) | ((unsigned)f2bf(a5.y * inv) << 16);
        ob.z = (unsigned)f2bf(a6.x * inv) | ((unsigned)f2bf(a6.y * inv) << 16);
        ob.w = (unsigned)f2bf(a7.x * inv) | ((unsigned)f2bf(a7.y * inv) << 16);
        *(uint4*)&aggLds[row * 136 + sub * 16] = oa;
        *(uint4*)&aggLds[row * 136 + sub * 16 + 8] = ob;
      } else {
        uint4 z = make_uint4(0, 0, 0, 0);
        *(uint4*)&aggLds[row * 136 + sub * 16] = z;
        *(uint4*)&aggLds[row * 136 + sub * 16 + 8] = z;
      }
    }
  }

  // ---- Phase B: MFMA (reads only this wave's 16 LDS rows; root term bf16) ----
  int r0 = blockIdx.x * 64 + w * 16;
  int c = l & 15;
  int rb = (l >> 4) << 2;
  int rowA = r0 + c;
  int rowAc = min(rowA, N - 1);
  const size_t goff = (size_t)rowAc * 128 + ((l >> 4) << 3);
  const unsigned short* aLds = &aggLds[(w * 16 + c) * 136 + ((l >> 4) << 3)];

  f32x4 acc[8];
#pragma unroll
  for (int nt = 0; nt < 8; ++nt) acc[nt] = (f32x4){0.f, 0.f, 0.f, 0.f};

#pragma unroll
  for (int kt = 0; kt < 4; ++kt) {
    s16x8 a = *(const s16x8*)(aLds + kt * 32);
#pragma unroll
    for (int nt = 0; nt < 8; ++nt) {
      s16x8 b;
      { uint4 q = *(const uint4*)(WlB + (((nt * 4 + kt) * 64 + l) << 3));
        b = *(const s16x8*)&q; }
      acc[nt] = __builtin_amdgcn_mfma_f32_16x16x32_bf16(a, b, acc[nt], 0, 0, 0);
    }
  }
#pragma unroll
  for (int kt = 0; kt < 4; ++kt) {
    s16x8 a;
    { uint4 q = *(const uint4*)(featbf + goff + kt * 32);
      a = *(const s16x8*)&q; }
#pragma unroll
    for (int nt = 0; nt < 8; ++nt) {
      s16x8 b;
      { uint4 q = *(const uint4*)(WrB + (((nt * 4 + kt) * 64 + l) << 3));
        b = *(const s16x8*)&q; }
      acc[nt] = __builtin_amdgcn_mfma_f32_16x16x32_bf16(a, b, acc[nt], 0, 0, 0);
    }
  }

  // ---- Phase C: bias + LN partials; reuse this wave's LDS rows; coalesced store ----
  float s = 0.f, s2 = 0.f;
#pragma unroll
  for (int nt = 0; nt < 8; ++nt) {
    float bv = bias[nt * 16 + c];
#pragma unroll
    for (int i = 0; i < 4; ++i) {
      float v = acc[nt][i] + bv;
      if (r0 + rb + i < N) { s += v; s2 += v * v; }
      aggLds[(w * 16 + rb + i) * 136 + nt * 16 + c] = f2bf(v);
    }
  }

#pragma unroll
  for (int j = 0; j < 4; ++j) {
    int idx = j * 64 + l;
    int riw = idx >> 4;          // row in wave 0..15
    int chunk = idx & 15;        // 16B chunk
    int row = r0 + riw;
    if (row < N) {
      uint4 o = *(const uint4*)&aggLds[(w * 16 + riw) * 136 + chunk * 8];
      *(uint4*)(out + (size_t)row * 128 + chunk * 8) = o;
    }
  }

#pragma unroll
  for (int off = 1; off < 64; off <<= 1) {
    s  += __shfl_xor(s, off);
    s2 += __shfl_xor(s2, off);
  }
  if (l == 0) {
    int bucket = (blockIdx.x * 4 + w) & 255;
    atomicAdd(&red[2 * bucket],     (double)s);
    atomicAdd(&red[2 * bucket + 1], (double)s2);
  }
}

// ---------------- normalize + affine + ReLU (stats reduced in-block), bf16 -> bf16 + fp8 ----------------

__global__ void __launch_bounds__(256) k_apply1(
    const unsigned short* __restrict__ h, unsigned short* __restrict__ o,
    unsigned int* __restrict__ of8,
    const double* __restrict__ red, double count,
    const float* __restrict__ gamma, const float* __restrict__ beta,
    size_t total8) {
  __shared__ double sh[256], sh2[256];
  __shared__ float sc[2];
  int t = threadIdx.x;
  sh[t] = red[2 * t]; sh2[t] = red[2 * t + 1];
  __syncthreads();
  for (int off = 128; off > 0; off >>= 1) {
    if (t < off) { sh[t] += sh[t + off]; sh2[t] += sh2[t + off]; }
    __syncthreads();
  }
  if (t == 0) {
    double mu = sh[0] / count;
    double var = sh2[0] / count - mu * mu;
    sc[0] = (float)mu;
    sc[1] = (float)(1.0 / sqrt(var + 1e-5));
  }
  __syncthreads();
  size_t i = (size_t)blockIdx.x * blockDim.x + t;
  if (i >= total8) return;
  float mu = sc[0], rs = sc[1];
  int c0 = (int)((i * 8) & 127);
  float4 g0 = *(const float4*)(gamma + c0);
  float4 g1 = *(const float4*)(gamma + c0 + 4);
  float4 b0 = *(const float4*)(beta + c0);
  float4 b1 = *(const float4*)(beta + c0 + 4);
  uint4 q = ((const uint4*)h)[i];
  float gg[8] = {g0.x, g0.y, g0.z, g0.w, g1.x, g1.y, g1.z, g1.w};
  float bb[8] = {b0.x, b0.y, b0.z, b0.w, b1.x, b1.y, b1.z, b1.w};
  uint4 ov;
  float y[8];
#pragma unroll
  for (int w = 0; w < 4; ++w) {
    unsigned int v = ((const unsigned int*)&q)[w];
    float x0 = __uint_as_float(v << 16);
    float x1 = __uint_as_float(v & 0xFFFF0000u);
    float y0 = fmaxf((x0 - mu) * rs * gg[2 * w] + bb[2 * w], 0.f);
    float y1 = fmaxf((x1 - mu) * rs * gg[2 * w + 1] + bb[2 * w + 1], 0.f);
    y[2 * w] = y0; y[2 * w + 1] = y1;
    ((unsigned int*)&ov)[w] = (unsigned)f2bf(y0) | ((unsigned)f2bf(y1) << 16);
  }
  ((uint4*)o)[i] = ov;
  ((uint2*)of8)[i] = pk8_fp8(y);
}

// ---------------- normalize + affine + ReLU + residual(bf16) -> fp32 ----------------

__global__ void __launch_bounds__(256) k_apply2(
    const unsigned short* __restrict__ h, const unsigned short* __restrict__ xres,
    float* __restrict__ o, const double* __restrict__ red, double count,
    const float* __restrict__ gamma, const float* __restrict__ beta,
    size_t total8) {
  __shared__ double sh[256], sh2[256];
  __shared__ float sc[2];
  int t = threadIdx.x;
  sh[t] = red[2 * t]; sh2[t] = red[2 * t + 1];
  __syncthreads();
  for (int off = 128; off > 0; off >>= 1) {
    if (t < off) { sh[t] += sh[t + off]; sh2[t] += sh2[t + off]; }
    __syncthreads();
  }
  if (t == 0) {
    double mu = sh[0] / count;
    double var = sh2[0] / count - mu * mu;
    sc[0] = (float)mu;
    sc[1] = (float)(1.0 / sqrt(var + 1e-5));
  }
  __syncthreads();
  size_t i = (size_t)blockIdx.x * blockDim.x + t;
  if (i >= total8) return;
  float mu = sc[0], rs = sc[1];
  int c0 = (int)((i * 8) & 127);
  float4 g0 = *(const float4*)(gamma + c0);
  float4 g1 = *(const float4*)(gamma + c0 + 4);
  float4 b0 = *(const float4*)(beta + c0);
  float4 b1 = *(const float4*)(beta + c0 + 4);
  uint4 q  = ((const uint4*)h)[i];
  uint4 qx = ((const uint4*)xres)[i];
  float gg[8] = {g0.x, g0.y, g0.z, g0.w, g1.x, g1.y, g1.z, g1.w};
  float bb[8] = {b0.x, b0.y, b0.z, b0.w, b1.x, b1.y, b1.z, b1.w};
  float out8[8];
#pragma unroll
  for (int w = 0; w < 4; ++w) {
    unsigned int v  = ((const unsigned int*)&q)[w];
    unsigned int vx = ((const unsigned int*)&qx)[w];
    float x0 = __uint_as_float(v << 16);
    float x1 = __uint_as_float(v & 0xFFFF0000u);
    float r0 = __uint_as_float(vx << 16);
    float r1 = __uint_as_float(vx & 0xFFFF0000u);
    out8[2 * w]     = fmaxf((x0 - mu) * rs * gg[2 * w] + bb[2 * w], 0.f) + r0;
    out8[2 * w + 1] = fmaxf((x1 - mu) * rs * gg[2 * w + 1] + bb[2 * w + 1], 0.f) + r1;
  }
  ((float4*)o)[i * 2]     = make_float4(out8[0], out8[1], out8[2], out8[3]);
  ((float4*)o)[i * 2 + 1] = make_float4(out8[4], out8[5], out8[6], out8[7]);
}

// ---------------- launch ----------------

extern "C" void kernel_launch(void* const* d_in, const int* in_sizes, int n_in,
                              void* d_out, int out_size, void* d_ws, size_t ws_size,
                              hipStream_t stream) {
  const float* x   = (const float*)d_in[0];
  const int*   ei  = (const int*)d_in[1];
  const float* Wl1 = (const float*)d_in[2];
  const float* bl1 = (const float*)d_in[3];
  const float* Wr1 = (const float*)d_in[4];
  const float* g1  = (const float*)d_in[5];
  const float* b1  = (const float*)d_in[6];
  const float* Wl2 = (const float*)d_in[7];
  const float* bl2 = (const float*)d_in[8];
  const float* Wr2 = (const float*)d_in[9];
  const float* g2  = (const float*)d_in[10];
  const float* b2  = (const float*)d_in[11];
  float* out = (float*)d_out;

  const int N = in_sizes[0] / 128;
  const int E = in_sizes[1] / 2;
  const int NB = (N + BMASK) >> BSHIFT;

  char* ws = (char*)d_ws;
  size_t off = 0;
  auto alloc = [&](size_t bytes) -> void* {
    void* p = ws + off;
    off = (off + bytes + 255) & ~(size_t)255;
    return p;
  };
  unsigned short* xh   = (unsigned short*)alloc((size_t)N * 128 * 2);
  unsigned short* hmm  = (unsigned short*)alloc((size_t)N * 128 * 2);
  unsigned short* h1n  = (unsigned short*)alloc((size_t)N * 128 * 2);
  unsigned int*   xf8  = (unsigned int*)alloc((size_t)N * 128);
  unsigned int*   h1f8 = (unsigned int*)alloc((size_t)N * 128);
  int*    ssrc   = (int*)alloc((size_t)E * 4);
  int*    rowptr = (int*)alloc((size_t)(N + 1) * 4);
  int*    bhist  = (int*)alloc((size_t)(NB + 1) * 4);   // contiguous with red: one memset
  double* red    = (double*)alloc(2 * 512 * sizeof(double));
  int*    boff   = (int*)alloc((size_t)(NB + 1) * 4);
  int*    bcur   = (int*)alloc((size_t)(NB + 1) * 4);
  unsigned short* Wl1b = (unsigned short*)alloc(128 * 128 * 2);
  unsigned short* Wr1b = (unsigned short*)alloc(128 * 128 * 2);
  unsigned short* Wl2b = (unsigned short*)alloc(128 * 128 * 2);
  unsigned short* Wr2b = (unsigned short*)alloc(128 * 128 * 2);
  unsigned int* tmp = (unsigned int*)hmm;  // alias: consumed (k_csr) before k_fmm writes hmm
  (void)ws_size; (void)n_in; (void)out_size;

  const size_t total  = (size_t)N * 128;
  const size_t total8 = total / 8;
  const int applyGrid = (int)((total8 + 255) / 256);

  // single memset covers bhist + red (allocated adjacently)
  hipMemsetAsync(bhist, 0, (size_t)((char*)(red + 2 * 512) - (char*)bhist), stream);

  k_prep<<<applyGrid + 32 + 128, 256, 0, stream>>>(
      x, xh, xf8, total8, applyGrid,
      Wl1, Wr1, Wl2, Wr2, Wl1b, Wr1b, Wl2b, Wr2b,
      ei, E, bhist, NB);
  k_bscan<<<1, 256, 0, stream>>>(bhist, boff, bcur, NB, E);
  k_part<<<(E + CHUNK - 1) / CHUNK, 512, 0, stream>>>(ei, E, bcur, tmp, NB);
  k_csr<<<NB, 256, 0, stream>>>(tmp, boff, rowptr, ssrc, N, NB, E);

  const int mmGrid = (N + 63) / 64;

  // ---- layer 1 ----
  k_fmm<<<mmGrid, 256, 0, stream>>>((const unsigned char*)xf8, xh, rowptr, ssrc,
                                    Wl1b, Wr1b, bl1, hmm, red, N);
  k_apply1<<<applyGrid, 256, 0, stream>>>(hmm, h1n, h1f8, red, (double)total, g1, b1, total8);

  // ---- layer 2 ----
  k_fmm<<<mmGrid, 256, 0, stream>>>((const unsigned char*)h1f8, h1n, rowptr, ssrc,
                                    Wl2b, Wr2b, bl2, hmm, red + 512, N);
  k_apply2<<<applyGrid, 256, 0, stream>>>(hmm, xh, out, red + 512, (double)total, g2, b2, total8);
}

// Round 14
// 214.041 us; speedup vs baseline: 1.2032x; 1.0358x over previous
//
#include <hip/hip_runtime.h>
#include <hip/hip_cooperative_groups.h>

namespace cg = cooperative_groups;

typedef float  f32x4 __attribute__((ext_vector_type(4)));
typedef float  f32x2 __attribute__((ext_vector_type(2)));
typedef short  s16x8 __attribute__((ext_vector_type(8)));

#define BSHIFT 7
#define BMASK  127
#define CHUNK  8192

__device__ __forceinline__ unsigned short f2bf(float f) {
  unsigned int u = __float_as_uint(f);
  unsigned int r = (u + 0x7FFFu + ((u >> 16) & 1u)) >> 16;
  return (unsigned short)r;
}

__device__ __forceinline__ uint2 pk8_fp8(const float* y) {
  int p0 = __builtin_amdgcn_cvt_pk_fp8_f32(y[0], y[1], 0, false);
  p0     = __builtin_amdgcn_cvt_pk_fp8_f32(y[2], y[3], p0, true);
  int p1 = __builtin_amdgcn_cvt_pk_fp8_f32(y[4], y[5], 0, false);
  p1     = __builtin_amdgcn_cvt_pk_fp8_f32(y[6], y[7], p1, true);
  return make_uint2((unsigned)p0, (unsigned)p1);
}

// ---------------- combined prep: x->bf16+fp8 cvt | weight cvt | dst histogram ----------------

__global__ void __launch_bounds__(256) k_prep(
    const float* __restrict__ x, unsigned short* __restrict__ xh,
    unsigned int* __restrict__ xf8, size_t total8, int cvtBlocks,
    const float* __restrict__ W0, const float* __restrict__ W1,
    const float* __restrict__ W2, const float* __restrict__ W3,
    unsigned short* __restrict__ B0, unsigned short* __restrict__ B1,
    unsigned short* __restrict__ B2, unsigned short* __restrict__ B3,
    const int* __restrict__ ei, int E, int* __restrict__ bhist, int NB) {
  __shared__ int h[1024];
  int b = blockIdx.x;
  if (b < cvtBlocks) {
    size_t i = (size_t)b * 256 + threadIdx.x;
    if (i >= total8) return;
    float4 a = ((const float4*)x)[i * 2];
    float4 c = ((const float4*)x)[i * 2 + 1];
    uint4 o;
    o.x = (unsigned)f2bf(a.x) | ((unsigned)f2bf(a.y) << 16);
    o.y = (unsigned)f2bf(a.z) | ((unsigned)f2bf(a.w) << 16);
    o.z = (unsigned)f2bf(c.x) | ((unsigned)f2bf(c.y) << 16);
    o.w = (unsigned)f2bf(c.z) | ((unsigned)f2bf(c.w) << 16);
    ((uint4*)xh)[i] = o;
    float y[8] = {a.x, a.y, a.z, a.w, c.x, c.y, c.z, c.w};
    ((uint2*)xf8)[i] = pk8_fp8(y);
  } else if (b < cvtBlocks + 32) {
    int gt = (b - cvtBlocks) * 256 + threadIdx.x;  // 8192 total
    int which = gt >> 11;
    const float* W = which == 0 ? W0 : which == 1 ? W1 : which == 2 ? W2 : W3;
    unsigned short* WB = which == 0 ? B0 : which == 1 ? B1 : which == 2 ? B2 : B3;
    int t = gt & 2047;
    int lane = t & 63, kt = (t >> 6) & 3, nt = t >> 8;
    int col = nt * 16 + (lane & 15);
    int k0  = kt * 32 + ((lane >> 4) << 3);
#pragma unroll
    for (int j = 0; j < 8; ++j)
      WB[(((nt * 4 + kt) * 64 + lane) << 3) + j] = f2bf(W[(size_t)(k0 + j) * 128 + col]);
  } else {
    int bb = b - cvtBlocks - 32;   // 0..127
    for (int i = threadIdx.x; i < 1024; i += 256) h[i] = 0;
    __syncthreads();
    int i0 = bb * 256 + threadIdx.x;
    int stride = 128 * 256;
    for (int e = i0; e < E; e += stride)
      atomicAdd(&h[ei[E + e] >> BSHIFT], 1);
    __syncthreads();
    for (int i = threadIdx.x; i < NB; i += 256)
      if (h[i]) atomicAdd(&bhist[i], h[i]);
  }
}

// ---------------- bucketed CSR build ----------------

__global__ void k_bscan(const int* __restrict__ bhist, int* __restrict__ boff,
                        int* __restrict__ bcur, int NB, int E) {
  __shared__ int tot[256];
  int t = threadIdx.x;
  int v[4]; int s = 0;
#pragma unroll
  for (int j = 0; j < 4; ++j) {
    int idx = t * 4 + j;
    v[j] = (idx < NB) ? bhist[idx] : 0;
    s += v[j];
  }
  tot[t] = s; __syncthreads();
  for (int off = 1; off < 256; off <<= 1) {
    int x = (t >= off) ? tot[t - off] : 0;
    __syncthreads();
    tot[t] += x;
    __syncthreads();
  }
  int excl = (t > 0) ? tot[t - 1] : 0;
#pragma unroll
  for (int j = 0; j < 4; ++j) {
    int idx = t * 4 + j;
    if (idx < NB) { boff[idx] = excl; bcur[idx] = excl; }
    excl += v[j];
  }
  if (t == 0) boff[NB] = E;
}

__global__ void __launch_bounds__(512) k_part(
    const int* __restrict__ ei, int E, int* __restrict__ bcur,
    unsigned int* __restrict__ tmp, int NB) {
  __shared__ int lh[1024], lbase[1024], lcur[1024];
  int t = threadIdx.x;
  int c0 = blockIdx.x * CHUNK;
  int cend = min(c0 + CHUNK, E);
  for (int i = t; i < NB; i += 512) lh[i] = 0;
  __syncthreads();
  for (int e = c0 + t; e < cend; e += 512)
    atomicAdd(&lh[ei[E + e] >> BSHIFT], 1);
  __syncthreads();
  for (int i = t; i < NB; i += 512) {
    int c = lh[i];
    lbase[i] = c ? atomicAdd(&bcur[i], c) : 0;
    lcur[i] = 0;
  }
  __syncthreads();
  for (int e = c0 + t; e < cend; e += 512) {
    int src = ei[e], dst = ei[E + e];
    int b = dst >> BSHIFT;
    int pos = lbase[b] + atomicAdd(&lcur[b], 1);
    tmp[pos] = ((unsigned)(dst & BMASK) << 25) | (unsigned)src;
  }
}

__global__ void __launch_bounds__(256) k_csr(
    const unsigned int* __restrict__ tmp, const int* __restrict__ boff,
    int* __restrict__ rowptr, int* __restrict__ ssrc, int N, int NB, int E) {
  __shared__ int cnt[128], sc[128], curs[128];
  int b = blockIdx.x;
  int t = threadIdx.x;
  int beg = boff[b], end = boff[b + 1];
  int nbase = b << BSHIFT;
  int nn = min(128, N - nbase);
  if (t < 128) cnt[t] = 0;
  __syncthreads();
  for (int i = beg + t; i < end; i += 256)
    atomicAdd(&cnt[tmp[i] >> 25], 1);
  __syncthreads();
  if (t < 128) sc[t] = cnt[t];
  __syncthreads();
  for (int off = 1; off < 128; off <<= 1) {
    int x = 0;
    if (t < 128 && t >= off) x = sc[t - off];
    __syncthreads();
    if (t < 128) sc[t] += x;
    __syncthreads();
  }
  if (t < nn) {
    int excl = sc[t] - cnt[t];
    rowptr[nbase + t] = beg + excl;
    curs[t] = excl;
  }
  __syncthreads();
  for (int i = beg + t; i < end; i += 256) {
    unsigned int p = tmp[i];
    int pos = beg + atomicAdd(&curs[p >> 25], 1);
    ssrc[pos] = (int)((p & 0x1FFFFFFu) << 7);   // byte offset into fp8 rows: src * 128
  }
  if (b == NB - 1 && t == 0) rowptr[N] = E;
}

// ================= fused fp8-gather + MFMA + LN(grid-sync) + apply =================
// Phases A-C as before (wave-autonomous, no block barriers); then grid.sync(),
// in-block stat reduction, and the LN/ReLU epilogue straight out of LDS.
// mode 0: emit bf16 + fp8 hidden; mode 1: emit fp32 out with bf16 residual.

__global__ void __launch_bounds__(256, 8) k_fmm_ln(
    const unsigned char* __restrict__ featf8, const unsigned short* __restrict__ featbf,
    const int* __restrict__ rowptr, const int* __restrict__ ssrc,
    const unsigned short* __restrict__ WlB, const unsigned short* __restrict__ WrB,
    const float* __restrict__ bias, const float* __restrict__ gamma,
    const float* __restrict__ beta, double* __restrict__ red,
    int N, double count, int mode,
    unsigned short* __restrict__ o_bf, unsigned int* __restrict__ o_f8,
    const unsigned short* __restrict__ xres, float* __restrict__ o_f32) {
  __shared__ __align__(16) unsigned short aggLds[64 * 136];  // 272B row stride
  __shared__ double shd[4][2];
  __shared__ float scb[2];
  int t = threadIdx.x;
  int l = t & 63, w = t >> 6;
  const char* fp = (const char*)featf8;

  // ---- Phase A: 8 groups/wave x 8 lanes; each group aggregates 2 nodes ----
  {
    int gg = l >> 3;
    int sub = l & 7;
    unsigned suboff = (unsigned)(sub * 16);
#pragma unroll
    for (int j = 0; j < 2; ++j) {
      int row = w * 16 + gg * 2 + j;
      int node = blockIdx.x * 64 + row;
      if (node < N) {
        int beg = rowptr[node], end = rowptr[node + 1];
        f32x2 a0 = {0.f, 0.f}, a1 = a0, a2 = a0, a3 = a0,
              a4 = a0, a5 = a0, a6 = a0, a7 = a0;
#define ACCQ(q) {                                                        \
          a0 += __builtin_amdgcn_cvt_pk_f32_fp8((q).x, false);           \
          a1 += __builtin_amdgcn_cvt_pk_f32_fp8((q).x, true);            \
          a2 += __builtin_amdgcn_cvt_pk_f32_fp8((q).y, false);           \
          a3 += __builtin_amdgcn_cvt_pk_f32_fp8((q).y, true);            \
          a4 += __builtin_amdgcn_cvt_pk_f32_fp8((q).z, false);           \
          a5 += __builtin_amdgcn_cvt_pk_f32_fp8((q).z, true);            \
          a6 += __builtin_amdgcn_cvt_pk_f32_fp8((q).w, false);           \
          a7 += __builtin_amdgcn_cvt_pk_f32_fp8((q).w, true);            \
        }
        int i = beg;
        for (; i + 4 <= end; i += 4) {
          unsigned o0 = (unsigned)ssrc[i]     + suboff;
          unsigned o1 = (unsigned)ssrc[i + 1] + suboff;
          unsigned o2 = (unsigned)ssrc[i + 2] + suboff;
          unsigned o3 = (unsigned)ssrc[i + 3] + suboff;
          uint4 q0 = *(const uint4*)(fp + o0);
          uint4 q1 = *(const uint4*)(fp + o1);
          uint4 q2 = *(const uint4*)(fp + o2);
          uint4 q3 = *(const uint4*)(fp + o3);
          ACCQ(q0); ACCQ(q1); ACCQ(q2); ACCQ(q3);
        }
        for (; i < end; ++i) {
          uint4 q = *(const uint4*)(fp + ((unsigned)ssrc[i] + suboff));
          ACCQ(q);
        }
#undef ACCQ
        float inv = __builtin_amdgcn_rcpf(fmaxf((float)(end - beg), 1.0f));
        uint4 oa, ob;
        oa.x = (unsigned)f2bf(a0.x * inv) | ((unsigned)f2bf(a0.y * inv) << 16);
        oa.y = (unsigned)f2bf(a1.x * inv) | ((unsigned)f2bf(a1.y * inv) << 16);
        oa.z = (unsigned)f2bf(a2.x * inv) | ((unsigned)f2bf(a2.y * inv) << 16);
        oa.w = (unsigned)f2bf(a3.x * inv) | ((unsigned)f2bf(a3.y * inv) << 16);
        ob.x = (unsigned)f2bf(a4.x * inv) | ((unsigned)f2bf(a4.y * inv) << 16);
        ob.y = (unsigned)f2bf(a5.x * inv) | ((unsigned)f2bf(a5.y * inv) << 16);
        ob.z = (unsigned)f2bf(a6.x * inv) | ((unsigned)f2bf(a6.y * inv) << 16);
        ob.w = (unsigned)f2bf(a7.x * inv) | ((unsigned)f2bf(a7.y * inv) << 16);
        *(uint4*)&aggLds[row * 136 + sub * 16] = oa;
        *(uint4*)&aggLds[row * 136 + sub * 16 + 8] = ob;
      } else {
        uint4 z = make_uint4(0, 0, 0, 0);
        *(uint4*)&aggLds[row * 136 + sub * 16] = z;
        *(uint4*)&aggLds[row * 136 + sub * 16 + 8] = z;
      }
    }
  }

  // ---- Phase B: MFMA (this wave's 16 LDS rows; root term bf16) ----
  int r0 = blockIdx.x * 64 + w * 16;
  int c = l & 15;
  int rb = (l >> 4) << 2;
  int rowA = r0 + c;
  int rowAc = min(rowA, N - 1);
  const size_t goff = (size_t)rowAc * 128 + ((l >> 4) << 3);
  const unsigned short* aLds = &aggLds[(w * 16 + c) * 136 + ((l >> 4) << 3)];

  f32x4 acc[8];
#pragma unroll
  for (int nt = 0; nt < 8; ++nt) acc[nt] = (f32x4){0.f, 0.f, 0.f, 0.f};

#pragma unroll
  for (int kt = 0; kt < 4; ++kt) {
    s16x8 a = *(const s16x8*)(aLds + kt * 32);
#pragma unroll
    for (int nt = 0; nt < 8; ++nt) {
      s16x8 b;
      { uint4 q = *(const uint4*)(WlB + (((nt * 4 + kt) * 64 + l) << 3));
        b = *(const s16x8*)&q; }
      acc[nt] = __builtin_amdgcn_mfma_f32_16x16x32_bf16(a, b, acc[nt], 0, 0, 0);
    }
  }
#pragma unroll
  for (int kt = 0; kt < 4; ++kt) {
    s16x8 a;
    { uint4 q = *(const uint4*)(featbf + goff + kt * 32);
      a = *(const s16x8*)&q; }
#pragma unroll
    for (int nt = 0; nt < 8; ++nt) {
      s16x8 b;
      { uint4 q = *(const uint4*)(WrB + (((nt * 4 + kt) * 64 + l) << 3));
        b = *(const s16x8*)&q; }
      acc[nt] = __builtin_amdgcn_mfma_f32_16x16x32_bf16(a, b, acc[nt], 0, 0, 0);
    }
  }

  // ---- Phase C: bias + LN partials; stage pre-LN tile (bf16) in this wave's LDS ----
  float s = 0.f, s2 = 0.f;
#pragma unroll
  for (int nt = 0; nt < 8; ++nt) {
    float bv = bias[nt * 16 + c];
#pragma unroll
    for (int i = 0; i < 4; ++i) {
      float v = acc[nt][i] + bv;
      if (r0 + rb + i < N) { s += v; s2 += v * v; }
      aggLds[(w * 16 + rb + i) * 136 + nt * 16 + c] = f2bf(v);
    }
  }
#pragma unroll
  for (int off = 1; off < 64; off <<= 1) {
    s  += __shfl_xor(s, off);
    s2 += __shfl_xor(s2, off);
  }
  if (l == 0) {
    int bucket = (blockIdx.x * 4 + w) & 255;
    atomicAdd(&red[2 * bucket],     (double)s);
    atomicAdd(&red[2 * bucket + 1], (double)s2);
  }

  // ---- grid-wide sync: all LN partials visible ----
  cg::this_grid().sync();

  // ---- in-block stat reduction (256 buckets) ----
  {
    double a = red[2 * t], b = red[2 * t + 1];
#pragma unroll
    for (int off = 1; off < 64; off <<= 1) {
      a += __shfl_xor(a, off);
      b += __shfl_xor(b, off);
    }
    if (l == 0) { shd[w][0] = a; shd[w][1] = b; }
    __syncthreads();
    if (t == 0) {
      double su = shd[0][0] + shd[1][0] + shd[2][0] + shd[3][0];
      double sq = shd[0][1] + shd[1][1] + shd[2][1] + shd[3][1];
      double mu = su / count;
      double var = sq / count - mu * mu;
      scb[0] = (float)mu;
      scb[1] = (float)(1.0 / sqrt(var + 1e-5));
    }
    __syncthreads();
  }
  float mu = scb[0], rs = scb[1];

  // ---- apply LN + ReLU (+residual) from LDS; coalesced emit ----
#pragma unroll
  for (int j = 0; j < 4; ++j) {
    int idx = j * 64 + l;
    int riw = idx >> 4;
    int chunk = idx & 15;
    int row = r0 + riw;
    if (row < N) {
      uint4 q = *(const uint4*)&aggLds[(w * 16 + riw) * 136 + chunk * 8];
      int c0 = chunk * 8;
      float4 g0 = *(const float4*)(gamma + c0);
      float4 g1 = *(const float4*)(gamma + c0 + 4);
      float4 b0 = *(const float4*)(beta + c0);
      float4 b1 = *(const float4*)(beta + c0 + 4);
      float gg[8] = {g0.x, g0.y, g0.z, g0.w, g1.x, g1.y, g1.z, g1.w};
      float bb[8] = {b0.x, b0.y, b0.z, b0.w, b1.x, b1.y, b1.z, b1.w};
      float y[8];
#pragma unroll
      for (int k = 0; k < 4; ++k) {
        unsigned int v = ((const unsigned int*)&q)[k];
        float x0 = __uint_as_float(v << 16);
        float x1 = __uint_as_float(v & 0xFFFF0000u);
        y[2 * k]     = fmaxf((x0 - mu) * rs * gg[2 * k] + bb[2 * k], 0.f);
        y[2 * k + 1] = fmaxf((x1 - mu) * rs * gg[2 * k + 1] + bb[2 * k + 1], 0.f);
      }
      if (mode == 0) {
        uint4 ov;
#pragma unroll
        for (int k = 0; k < 4; ++k)
          ((unsigned int*)&ov)[k] = (unsigned)f2bf(y[2 * k]) |
                                    ((unsigned)f2bf(y[2 * k + 1]) << 16);
        *(uint4*)(o_bf + (size_t)row * 128 + c0) = ov;
        ((uint2*)o_f8)[(size_t)row * 16 + chunk] = pk8_fp8(y);
      } else {
        uint4 qx = *(const uint4*)(xres + (size_t)row * 128 + c0);
        float4 oA, oB;
        {
          unsigned int vx = qx.x;
          oA.x = y[0] + __uint_as_float(vx << 16);
          oA.y = y[1] + __uint_as_float(vx & 0xFFFF0000u);
          vx = qx.y;
          oA.z = y[2] + __uint_as_float(vx << 16);
          oA.w = y[3] + __uint_as_float(vx & 0xFFFF0000u);
          vx = qx.z;
          oB.x = y[4] + __uint_as_float(vx << 16);
          oB.y = y[5] + __uint_as_float(vx & 0xFFFF0000u);
          vx = qx.w;
          oB.z = y[6] + __uint_as_float(vx << 16);
          oB.w = y[7] + __uint_as_float(vx & 0xFFFF0000u);
        }
        float* op = o_f32 + (size_t)row * 128 + c0;
        *(float4*)op = oA;
        *(float4*)(op + 4) = oB;
      }
    }
  }
}

// ================= fallback (non-cooperative) path: round-13 kernels =================

__global__ void __launch_bounds__(256, 8) k_fmm(
    const unsigned char* __restrict__ featf8, const unsigned short* __restrict__ featbf,
    const int* __restrict__ rowptr, const int* __restrict__ ssrc,
    const unsigned short* __restrict__ WlB, const unsigned short* __restrict__ WrB,
    const float* __restrict__ bias, unsigned short* __restrict__ out,
    double* __restrict__ red, int N) {
  __shared__ __align__(16) unsigned short aggLds[64 * 136];
  int t = threadIdx.x;
  int l = t & 63, w = t >> 6;
  const char* fp = (const char*)featf8;
  {
    int gg = l >> 3;
    int sub = l & 7;
    unsigned suboff = (unsigned)(sub * 16);
#pragma unroll
    for (int j = 0; j < 2; ++j) {
      int row = w * 16 + gg * 2 + j;
      int node = blockIdx.x * 64 + row;
      if (node < N) {
        int beg = rowptr[node], end = rowptr[node + 1];
        f32x2 a0 = {0.f, 0.f}, a1 = a0, a2 = a0, a3 = a0,
              a4 = a0, a5 = a0, a6 = a0, a7 = a0;
#define ACCQ(q) {                                                        \
          a0 += __builtin_amdgcn_cvt_pk_f32_fp8((q).x, false);           \
          a1 += __builtin_amdgcn_cvt_pk_f32_fp8((q).x, true);            \
          a2 += __builtin_amdgcn_cvt_pk_f32_fp8((q).y, false);           \
          a3 += __builtin_amdgcn_cvt_pk_f32_fp8((q).y, true);            \
          a4 += __builtin_amdgcn_cvt_pk_f32_fp8((q).z, false);           \
          a5 += __builtin_amdgcn_cvt_pk_f32_fp8((q).z, true);            \
          a6 += __builtin_amdgcn_cvt_pk_f32_fp8((q).w, false);           \
          a7 += __builtin_amdgcn_cvt_pk_f32_fp8((q).w, true);            \
        }
        int i = beg;
        for (; i + 4 <= end; i += 4) {
          unsigned o0 = (unsigned)ssrc[i]     + suboff;
          unsigned o1 = (unsigned)ssrc[i + 1] + suboff;
          unsigned o2 = (unsigned)ssrc[i + 2] + suboff;
          unsigned o3 = (unsigned)ssrc[i + 3] + suboff;
          uint4 q0 = *(const uint4*)(fp + o0);
          uint4 q1 = *(const uint4*)(fp + o1);
          uint4 q2 = *(const uint4*)(fp + o2);
          uint4 q3 = *(const uint4*)(fp + o3);
          ACCQ(q0); ACCQ(q1); ACCQ(q2); ACCQ(q3);
        }
        for (; i < end; ++i) {
          uint4 q = *(const uint4*)(fp + ((unsigned)ssrc[i] + suboff));
          ACCQ(q);
        }
#undef ACCQ
        float inv = __builtin_amdgcn_rcpf(fmaxf((float)(end - beg), 1.0f));
        uint4 oa, ob;
        oa.x = (unsigned)f2bf(a0.x * inv) | ((unsigned)f2bf(a0.y * inv) << 16);
        oa.y = (unsigned)f2bf(a1.x * inv) | ((unsigned)f2bf(a1.y * inv) << 16);
        oa.z = (unsigned)f2bf(a2.x * inv) | ((unsigned)f2bf(a2.y * inv) << 16);
        oa.w = (unsigned)f2bf(a3.x * inv) | ((unsigned)f2bf(a3.y * inv) << 16);
        ob.x = (unsigned)f2bf(a4.x * inv) | ((unsigned)f2bf(a4.y * inv) << 16);
        ob.y = (unsigned)f2bf(a5.x * inv) | ((unsigned)f2bf(a5.y * inv) << 16);
        ob.z = (unsigned)f2bf(a6.x * inv) | ((unsigned)f2bf(a6.y * inv) << 16);
        ob.w = (unsigned)f2bf(a7.x * inv) | ((unsigned)f2bf(a7.y * inv) << 16);
        *(uint4*)&aggLds[row * 136 + sub * 16] = oa;
        *(uint4*)&aggLds[row * 136 + sub * 16 + 8] = ob;
      } else {
        uint4 z = make_uint4(0, 0, 0, 0);
        *(uint4*)&aggLds[row * 136 + sub * 16] = z;
        *(uint4*)&aggLds[row * 136 + sub * 16 + 8] = z;
      }
    }
  }
  int r0 = blockIdx.x * 64 + w * 16;
  int c = l & 15;
  int rb = (l >> 4) << 2;
  int rowA = r0 + c;
  int rowAc = min(rowA, N - 1);
  const size_t goff = (size_t)rowAc * 128 + ((l >> 4) << 3);
  const unsigned short* aLds = &aggLds[(w * 16 + c) * 136 + ((l >> 4) << 3)];
  f32x4 acc[8];
#pragma unroll
  for (int nt = 0; nt < 8; ++nt) acc[nt] = (f32x4){0.f, 0.f, 0.f, 0.f};
#pragma unroll
  for (int kt = 0; kt < 4; ++kt) {
    s16x8 a = *(const s16x8*)(aLds + kt * 32);
#pragma unroll
    for (int nt = 0; nt < 8; ++nt) {
      s16x8 b;
      { uint4 q = *(const uint4*)(WlB + (((nt * 4 + kt) * 64 + l) << 3));
        b = *(const s16x8*)&q; }
      acc[nt] = __builtin_amdgcn_mfma_f32_16x16x32_bf16(a, b, acc[nt], 0, 0, 0);
    }
  }
#pragma unroll
  for (int kt = 0; kt < 4; ++kt) {
    s16x8 a;
    { uint4 q = *(const uint4*)(featbf + goff + kt * 32);
      a = *(const s16x8*)&q; }
#pragma unroll
    for (int nt = 0; nt < 8; ++nt) {
      s16x8 b;
      { uint4 q = *(const uint4*)(WrB + (((nt * 4 + kt) * 64 + l) << 3));
        b = *(const s16x8*)&q; }
      acc[nt] = __builtin_amdgcn_mfma_f32_16x16x32_bf16(a, b, acc[nt], 0, 0, 0);
    }
  }
  float s = 0.f, s2 = 0.f;
#pragma unroll
  for (int nt = 0; nt < 8; ++nt) {
    float bv = bias[nt * 16 + c];
#pragma unroll
    for (int i = 0; i < 4; ++i) {
      float v = acc[nt][i] + bv;
      if (r0 + rb + i < N) { s += v; s2 += v * v; }
      aggLds[(w * 16 + rb + i) * 136 + nt * 16 + c] = f2bf(v);
    }
  }
#pragma unroll
  for (int j = 0; j < 4; ++j) {
    int idx = j * 64 + l;
    int riw = idx >> 4;
    int chunk = idx & 15;
    int row = r0 + riw;
    if (row < N) {
      uint4 o = *(const uint4*)&aggLds[(w * 16 + riw) * 136 + chunk * 8];
      *(uint4*)(out + (size_t)row * 128 + chunk * 8) = o;
    }
  }
#pragma unroll
  for (int off = 1; off < 64; off <<= 1) {
    s  += __shfl_xor(s, off);
    s2 += __shfl_xor(s2, off);
  }
  if (l == 0) {
    int bucket = (blockIdx.x * 4 + w) & 255;
    atomicAdd(&red[2 * bucket],     (double)s);
    atomicAdd(&red[2 * bucket + 1], (double)s2);
  }
}

__global__ void __launch_bounds__(256) k_apply1(
    const unsigned short* __restrict__ h, unsigned short* __restrict__ o,
    unsigned int* __restrict__ of8,
    const double* __restrict__ red, double count,
    const float* __restrict__ gamma, const float* __restrict__ beta,
    size_t total8) {
  __shared__ double sh[256], sh2[256];
  __shared__ float sc[2];
  int t = threadIdx.x;
  sh[t] = red[2 * t]; sh2[t] = red[2 * t + 1];
  __syncthreads();
  for (int off = 128; off > 0; off >>= 1) {
    if (t < off) { sh[t] += sh[t + off]; sh2[t] += sh2[t + off]; }
    __syncthreads();
  }
  if (t == 0) {
    double mu = sh[0] / count;
    double var = sh2[0] / count - mu * mu;
    sc[0] = (float)mu;
    sc[1] = (float)(1.0 / sqrt(var + 1e-5));
  }
  __syncthreads();
  size_t i = (size_t)blockIdx.x * blockDim.x + t;
  if (i >= total8) return;
  float mu = sc[0], rs = sc[1];
  int c0 = (int)((i * 8) & 127);
  float4 g0 = *(const float4*)(gamma + c0);
  float4 g1 = *(const float4*)(gamma + c0 + 4);
  float4 b0 = *(const float4*)(beta + c0);
  float4 b1 = *(const float4*)(beta + c0 + 4);
  uint4 q = ((const uint4*)h)[i];
  float gg[8] = {g0.x, g0.y, g0.z, g0.w, g1.x, g1.y, g1.z, g1.w};
  float bb[8] = {b0.x, b0.y, b0.z, b0.w, b1.x, b1.y, b1.z, b1.w};
  uint4 ov;
  float y[8];
#pragma unroll
  for (int w = 0; w < 4; ++w) {
    unsigned int v = ((const unsigned int*)&q)[w];
    float x0 = __uint_as_float(v << 16);
    float x1 = __uint_as_float(v & 0xFFFF0000u);
    float y0 = fmaxf((x0 - mu) * rs * gg[2 * w] + bb[2 * w], 0.f);
    float y1 = fmaxf((x1 - mu) * rs * gg[2 * w + 1] + bb[2 * w + 1], 0.f);
    y[2 * w] = y0; y[2 * w + 1] = y1;
    ((unsigned int*)&ov)[w] = (unsigned)f2bf(y0) | ((unsigned)f2bf(y1) << 16);
  }
  ((uint4*)o)[i] = ov;
  ((uint2*)of8)[i] = pk8_fp8(y);
}

__global__ void __launch_bounds__(256) k_apply2(
    const unsigned short* __restrict__ h, const unsigned short* __restrict__ xres,
    float* __restrict__ o, const double* __restrict__ red, double count,
    const float* __restrict__ gamma, const float* __restrict__ beta,
    size_t total8) {
  __shared__ double sh[256], sh2[256];
  __shared__ float sc[2];
  int t = threadIdx.x;
  sh[t] = red[2 * t]; sh2[t] = red[2 * t + 1];
  __syncthreads();
  for (int off = 128; off > 0; off >>= 1) {
    if (t < off) { sh[t] += sh[t + off]; sh2[t] += sh2[t + off]; }
    __syncthreads();
  }
  if (t == 0) {
    double mu = sh[0] / count;
    double var = sh2[0] / count - mu * mu;
    sc[0] = (float)mu;
    sc[1] = (float)(1.0 / sqrt(var + 1e-5));
  }
  __syncthreads();
  size_t i = (size_t)blockIdx.x * blockDim.x + t;
  if (i >= total8) return;
  float mu = sc[0], rs = sc[1];
  int c0 = (int)((i * 8) & 127);
  float4 g0 = *(const float4*)(gamma + c0);
  float4 g1 = *(const float4*)(gamma + c0 + 4);
  float4 b0 = *(const float4*)(beta + c0);
  float4 b1 = *(const float4*)(beta + c0 + 4);
  uint4 q  = ((const uint4*)h)[i];
  uint4 qx = ((const uint4*)xres)[i];
  float gg[8] = {g0.x, g0.y, g0.z, g0.w, g1.x, g1.y, g1.z, g1.w};
  float bb[8] = {b0.x, b0.y, b0.z, b0.w, b1.x, b1.y, b1.z, b1.w};
  float out8[8];
#pragma unroll
  for (int w = 0; w < 4; ++w) {
    unsigned int v  = ((const unsigned int*)&q)[w];
    unsigned int vx = ((const unsigned int*)&qx)[w];
    float x0 = __uint_as_float(v << 16);
    float x1 = __uint_as_float(v & 0xFFFF0000u);
    float r0 = __uint_as_float(vx << 16);
    float r1 = __uint_as_float(vx & 0xFFFF0000u);
    out8[2 * w]     = fmaxf((x0 - mu) * rs * gg[2 * w] + bb[2 * w], 0.f) + r0;
    out8[2 * w + 1] = fmaxf((x1 - mu) * rs * gg[2 * w + 1] + bb[2 * w + 1], 0.f) + r1;
  }
  ((float4*)o)[i * 2]     = make_float4(out8[0], out8[1], out8[2], out8[3]);
  ((float4*)o)[i * 2 + 1] = make_float4(out8[4], out8[5], out8[6], out8[7]);
}

// ---------------- launch ----------------

extern "C" void kernel_launch(void* const* d_in, const int* in_sizes, int n_in,
                              void* d_out, int out_size, void* d_ws, size_t ws_size,
                              hipStream_t stream) {
  const float* x   = (const float*)d_in[0];
  const int*   ei  = (const int*)d_in[1];
  const float* Wl1 = (const float*)d_in[2];
  const float* bl1 = (const float*)d_in[3];
  const float* Wr1 = (const float*)d_in[4];
  const float* g1  = (const float*)d_in[5];
  const float* b1  = (const float*)d_in[6];
  const float* Wl2 = (const float*)d_in[7];
  const float* bl2 = (const float*)d_in[8];
  const float* Wr2 = (const float*)d_in[9];
  const float* g2  = (const float*)d_in[10];
  const float* b2  = (const float*)d_in[11];
  float* out = (float*)d_out;

  const int N = in_sizes[0] / 128;
  const int E = in_sizes[1] / 2;
  const int NB = (N + BMASK) >> BSHIFT;

  char* ws = (char*)d_ws;
  size_t off = 0;
  auto alloc = [&](size_t bytes) -> void* {
    void* p = ws + off;
    off = (off + bytes + 255) & ~(size_t)255;
    return p;
  };
  unsigned short* xh   = (unsigned short*)alloc((size_t)N * 128 * 2);
  unsigned short* hmm  = (unsigned short*)alloc((size_t)N * 128 * 2);
  unsigned short* h1n  = (unsigned short*)alloc((size_t)N * 128 * 2);
  unsigned int*   xf8  = (unsigned int*)alloc((size_t)N * 128);
  unsigned int*   h1f8 = (unsigned int*)alloc((size_t)N * 128);
  int*    ssrc   = (int*)alloc((size_t)E * 4);
  int*    rowptr = (int*)alloc((size_t)(N + 1) * 4);
  int*    bhist  = (int*)alloc((size_t)(NB + 1) * 4);   // contiguous with red: one memset
  double* red    = (double*)alloc(2 * 512 * sizeof(double));
  int*    boff   = (int*)alloc((size_t)(NB + 1) * 4);
  int*    bcur   = (int*)alloc((size_t)(NB + 1) * 4);
  unsigned short* Wl1b = (unsigned short*)alloc(128 * 128 * 2);
  unsigned short* Wr1b = (unsigned short*)alloc(128 * 128 * 2);
  unsigned short* Wl2b = (unsigned short*)alloc(128 * 128 * 2);
  unsigned short* Wr2b = (unsigned short*)alloc(128 * 128 * 2);
  unsigned int* tmp = (unsigned int*)hmm;  // alias: consumed (k_csr) before fmm writes
  (void)ws_size; (void)n_in; (void)out_size;

  const size_t total  = (size_t)N * 128;
  const size_t total8 = total / 8;
  const int applyGrid = (int)((total8 + 255) / 256);

  hipMemsetAsync(bhist, 0, (size_t)((char*)(red + 2 * 512) - (char*)bhist), stream);

  k_prep<<<applyGrid + 32 + 128, 256, 0, stream>>>(
      x, xh, xf8, total8, applyGrid,
      Wl1, Wr1, Wl2, Wr2, Wl1b, Wr1b, Wl2b, Wr2b,
      ei, E, bhist, NB);
  k_bscan<<<1, 256, 0, stream>>>(bhist, boff, bcur, NB, E);
  k_part<<<(E + CHUNK - 1) / CHUNK, 512, 0, stream>>>(ei, E, bcur, tmp, NB);
  k_csr<<<NB, 256, 0, stream>>>(tmp, boff, rowptr, ssrc, N, NB, E);

  const int mmGrid = (N + 63) / 64;

  // cooperative-capacity check (host-side queries; deterministic)
  int coop = 0;
  hipDeviceGetAttribute(&coop, hipDeviceAttributeCooperativeLaunch, 0);
  int maxBlocksPerCU = 0;
  hipOccupancyMaxActiveBlocksPerMultiprocessor(&maxBlocksPerCU, (const void*)k_fmm_ln, 256, 0);
  hipDeviceProp_t prop;
  hipGetDeviceProperties(&prop, 0);
  bool fused = coop && ((long)maxBlocksPerCU * prop.multiProcessorCount >= mmGrid);

  if (fused) {
    const unsigned char* xf8c  = (const unsigned char*)xf8;
    const unsigned char* h1f8c = (const unsigned char*)h1f8;
    int Nv = N; double cnt = (double)total;
    int m0 = 0, m1 = 1;
    double* red1 = red; double* red2 = red + 512;
    const unsigned short* xhc = xh;
    const unsigned short* h1nc = h1n;
    unsigned short* nb = nullptr; unsigned int* nf8 = nullptr;
    const unsigned short* nx = nullptr; float* nf = nullptr;

    void* a1[] = {(void*)&xf8c, (void*)&xhc, (void*)&rowptr, (void*)&ssrc,
                  (void*)&Wl1b, (void*)&Wr1b, (void*)&bl1, (void*)&g1, (void*)&b1,
                  (void*)&red1, (void*)&Nv, (void*)&cnt, (void*)&m0,
                  (void*)&h1n, (void*)&h1f8, (void*)&nx, (void*)&nf};
    hipLaunchCooperativeKernel((void*)k_fmm_ln, dim3(mmGrid), dim3(256), a1, 0, stream);

    void* a2[] = {(void*)&h1f8c, (void*)&h1nc, (void*)&rowptr, (void*)&ssrc,
                  (void*)&Wl2b, (void*)&Wr2b, (void*)&bl2, (void*)&g2, (void*)&b2,
                  (void*)&red2, (void*)&Nv, (void*)&cnt, (void*)&m1,
                  (void*)&nb, (void*)&nf8, (void*)&xhc, (void*)&out};
    hipLaunchCooperativeKernel((void*)k_fmm_ln, dim3(mmGrid), dim3(256), a2, 0, stream);
  } else {
    // fallback: round-13 separate kernels
    k_fmm<<<mmGrid, 256, 0, stream>>>((const unsigned char*)xf8, xh, rowptr, ssrc,
                                      Wl1b, Wr1b, bl1, hmm, red, N);
    k_apply1<<<applyGrid, 256, 0, stream>>>(hmm, h1n, h1f8, red, (double)total, g1, b1, total8);
    k_fmm<<<mmGrid, 256, 0, stream>>>((const unsigned char*)h1f8, h1n, rowptr, ssrc,
                                      Wl2b, Wr2b, bl2, hmm, red + 512, N);
    k_apply2<<<applyGrid, 256, 0, stream>>>(hmm, xh, out, red + 512, (double)total, g2, b2, total8);
  }
}